// Round 1
// baseline (330.505 us; speedup 1.0000x reference)
//
#include <hip/hip_runtime.h>
#include <cstdint>

// ---------------------------------------------------------------------------
// MultiHeadAttention fwd: B=2, S=2048, D=1024, H=16, d_k=64, fp32 in/out.
// Pipeline (all bf16 MFMA, fp32 accumulate):
//   1) convert q,k,v,w_q,w_k,w_v,w_o fp32 -> bf16 (workspace)
//   2) fused 3-way projection GEMM_bt (C = A*W^T + b), Q scaled by 0.125
//   3) flash attention (online softmax), 64 q-rows/block, KVBLK=128
//   4) output projection GEMM_bt -> fp32 d_out
// Workspace use: 7*8MB activations + 4*2MB weights = 64 MB.
// ---------------------------------------------------------------------------

typedef float  f32x4  __attribute__((ext_vector_type(4)));
typedef __bf16 bf16x8 __attribute__((ext_vector_type(8)));
typedef unsigned short u16;
typedef u16 u16x8 __attribute__((ext_vector_type(8)));

#define D_MODEL 1024
#define SEQ     2048
#define BATCH   2
#define NH      16
#define DKH     64
#define MTOT    (BATCH * SEQ)   // 4096
#define KVB     128

__device__ __forceinline__ u16 f2bf(float f) {
  uint32_t u = __builtin_bit_cast(uint32_t, f);
  u = u + 0x7fffu + ((u >> 16) & 1u);   // round-to-nearest-even
  return (u16)(u >> 16);
}

// async global->LDS, 16B per lane; dest is wave-uniform base + lane*16
__device__ __forceinline__ void gl_lds16(const void* g, void* l) {
  __builtin_amdgcn_global_load_lds(
      (__attribute__((address_space(1))) void*)(g),
      (__attribute__((address_space(3))) void*)(l), 16, 0, 0);
}

// ---------------------------------------------------------------------------
__global__ __launch_bounds__(256) void cvt_f32_bf16(
    const float* __restrict__ in, u16* __restrict__ out, int n4) {
  int i = blockIdx.x * 256 + threadIdx.x;
  if (i >= n4) return;
  float4 v = reinterpret_cast<const float4*>(in)[i];
  u16 o0 = f2bf(v.x), o1 = f2bf(v.y), o2 = f2bf(v.z), o3 = f2bf(v.w);
  uint32_t p0 = (uint32_t)o0 | ((uint32_t)o1 << 16);
  uint32_t p1 = (uint32_t)o2 | ((uint32_t)o3 << 16);
  reinterpret_cast<uint2*>(out)[i] = make_uint2(p0, p1);
}

// ---------------------------------------------------------------------------
// C[M][N] = A[M][K] * W[N][K]^T, bias added, then scaled. 128x128 tile,
// 256 thr (4 waves, each 64x64 = 4x4 fragments of 16x16x32 bf16 MFMA).
template <bool BF16OUT>
__device__ __forceinline__ void gemm_bt_body(
    const u16* __restrict__ A, const u16* __restrict__ W,
    const float* __restrict__ bias, void* __restrict__ Cout,
    int N, int K, float scale, int bidx) {
  __shared__ u16 As[128][64];
  __shared__ u16 Bs[128][64];
  const int nbx = N / 128;
  const int bx = bidx % nbx, by = bidx / nbx;
  const int tid = threadIdx.x, wave = tid >> 6, lane = tid & 63;
  const int l15 = lane & 15, lg = lane >> 4;
  const int wr = wave >> 1, wc = wave & 1;
  f32x4 acc[4][4] = {};
  const int rA = by * 128 + (lane >> 3);
  const int rB = bx * 128 + (lane >> 3);
  const int ccol = (lane & 7) * 8;

  for (int kt = 0; kt < K; kt += 64) {
    for (int c = wave; c < 16; c += 4) {
      gl_lds16(A + (size_t)(rA + 8 * c) * K + kt + ccol, &As[8 * c][0]);
      gl_lds16(W + (size_t)(rB + 8 * c) * K + kt + ccol, &Bs[8 * c][0]);
    }
    __syncthreads();
#pragma unroll
    for (int kc = 0; kc < 2; ++kc) {
      bf16x8 af[4], bw[4];
#pragma unroll
      for (int m = 0; m < 4; ++m)
        af[m] = *(const bf16x8*)&As[wr * 64 + m * 16 + l15][kc * 32 + 8 * lg];
#pragma unroll
      for (int n = 0; n < 4; ++n)
        bw[n] = *(const bf16x8*)&Bs[wc * 64 + n * 16 + l15][kc * 32 + 8 * lg];
#pragma unroll
      for (int m = 0; m < 4; ++m)
#pragma unroll
        for (int n = 0; n < 4; ++n)
          acc[m][n] = __builtin_amdgcn_mfma_f32_16x16x32_bf16(
              af[m], bw[n], acc[m][n], 0, 0, 0);
    }
    __syncthreads();
  }
  // epilogue: D element (reg j, lane l) = D[4*(l>>4)+j][l&15]  (m89-verified)
#pragma unroll
  for (int n = 0; n < 4; ++n) {
    int col = bx * 128 + wc * 64 + n * 16 + l15;
    float bv = bias[col];
#pragma unroll
    for (int m = 0; m < 4; ++m) {
      int row0 = by * 128 + wr * 64 + m * 16 + 4 * lg;
#pragma unroll
      for (int j = 0; j < 4; ++j) {
        float v = (acc[m][n][j] + bv) * scale;
        if (BF16OUT)
          ((u16*)Cout)[(size_t)(row0 + j) * N + col] = f2bf(v);
        else
          ((float*)Cout)[(size_t)(row0 + j) * N + col] = v;
      }
    }
  }
}

__global__ __launch_bounds__(256) void proj_kernel(
    const u16* qb, const u16* kb, const u16* vb,
    const u16* wq, const u16* wk, const u16* wv,
    const float* b_q, const float* b_k, const float* b_v,
    u16* Qp, u16* Kp, u16* Vp) {
  int z = blockIdx.y;
  const u16* A = (z == 0) ? qb : (z == 1) ? kb : vb;
  const u16* W = (z == 0) ? wq : (z == 1) ? wk : wv;
  const float* bi = (z == 0) ? b_q : (z == 1) ? b_k : b_v;
  u16* O = (z == 0) ? Qp : (z == 1) ? Kp : Vp;
  float scale = (z == 0) ? 0.125f : 1.0f;  // fold 1/sqrt(d_k) into Q
  gemm_bt_body<true>(A, W, bi, O, D_MODEL, D_MODEL, scale, blockIdx.x);
}

__global__ __launch_bounds__(256) void oproj_kernel(
    const u16* Op, const u16* wo, const float* b_o, float* out) {
  gemm_bt_body<false>(Op, wo, b_o, out, D_MODEL, D_MODEL, 1.0f, blockIdx.x);
}

// ---------------------------------------------------------------------------
// Flash attention. grid (S/64, H, B), 256 thr. Wave w owns q-rows [w*16,w*16+16).
__global__ __launch_bounds__(256) void attn_kernel(
    const u16* __restrict__ Qp, const u16* __restrict__ Kp,
    const u16* __restrict__ Vp, u16* __restrict__ Op) {
  __shared__ u16 Qs[64][64];
  __shared__ u16 Ks[KVB][64];
  __shared__ u16 Vt[64][KVB + 8];        // V^T [dk][kv], padded
  __shared__ u16 Pl[4][16][KVB + 8];     // per-wave P relayout buffer
  const int qt = blockIdx.x, h = blockIdx.y, b = blockIdx.z;
  const int tid = threadIdx.x, wave = tid >> 6, lane = tid & 63;
  const int l15 = lane & 15, lg = lane >> 4;
  const int qrow0 = b * SEQ + qt * 64;

  for (int c = wave; c < 8; c += 4)
    gl_lds16(Qp + (size_t)(qrow0 + 8 * c + (lane >> 3)) * D_MODEL + h * DKH +
                 (lane & 7) * 8,
             &Qs[8 * c][0]);
  __syncthreads();
  bf16x8 qf[2];
#pragma unroll
  for (int kc = 0; kc < 2; ++kc)
    qf[kc] = *(const bf16x8*)&Qs[wave * 16 + l15][kc * 32 + 8 * lg];

  float mrow[4], lrow[4];
  f32x4 acc[4] = {};
#pragma unroll
  for (int j = 0; j < 4; ++j) { mrow[j] = -1e30f; lrow[j] = 0.f; }

  const int vrp = tid >> 2;          // 0..63: kv row-pair
  const int vdk = (tid & 3) * 16;    // dk col base

  for (int kt = 0; kt < SEQ / KVB; ++kt) {
    const int kv0 = b * SEQ + kt * KVB;
    for (int c = wave; c < 16; c += 4)
      gl_lds16(Kp + (size_t)(kv0 + 8 * c + (lane >> 3)) * D_MODEL + h * DKH +
                   (lane & 7) * 8,
               &Ks[8 * c][0]);
    {  // transpose-stage V: [kv][dk] -> Vt[dk][kv], 2 kv packed per b32 write
      const u16* vs = Vp + (size_t)(kv0 + vrp * 2) * D_MODEL + h * DKH + vdk;
      u16x8 r0  = *(const u16x8*)(vs);
      u16x8 r0b = *(const u16x8*)(vs + 8);
      u16x8 r1  = *(const u16x8*)(vs + D_MODEL);
      u16x8 r1b = *(const u16x8*)(vs + D_MODEL + 8);
#pragma unroll
      for (int d = 0; d < 8; ++d) {
        uint32_t w0 = (uint32_t)r0[d]  | ((uint32_t)r1[d]  << 16);
        uint32_t w1 = (uint32_t)r0b[d] | ((uint32_t)r1b[d] << 16);
        *(uint32_t*)&Vt[vdk + d][vrp * 2]     = w0;
        *(uint32_t*)&Vt[vdk + 8 + d][vrp * 2] = w1;
      }
    }
    __syncthreads();

    // QK^T: D[q_local][kv_local], q_local = 4*lg+j, kv_local = n*16+l15
    f32x4 s[KVB / 16] = {};
#pragma unroll
    for (int n = 0; n < KVB / 16; ++n) {
#pragma unroll
      for (int kc = 0; kc < 2; ++kc) {
        bf16x8 kf = *(const bf16x8*)&Ks[n * 16 + l15][kc * 32 + 8 * lg];
        s[n] = __builtin_amdgcn_mfma_f32_16x16x32_bf16(qf[kc], kf, s[n], 0, 0, 0);
      }
    }
    // online softmax (row r = 4*lg+j; reduce across the 16-lane group)
    float corr[4];
#pragma unroll
    for (int j = 0; j < 4; ++j) {
      float v = s[0][j];
#pragma unroll
      for (int n = 1; n < KVB / 16; ++n) v = fmaxf(v, s[n][j]);
      v = fmaxf(v, __shfl_xor(v, 1, 64));
      v = fmaxf(v, __shfl_xor(v, 2, 64));
      v = fmaxf(v, __shfl_xor(v, 4, 64));
      v = fmaxf(v, __shfl_xor(v, 8, 64));
      float mnew = fmaxf(mrow[j], v);
      corr[j] = __expf(mrow[j] - mnew);
      mrow[j] = mnew;
    }
    float rs[4] = {0.f, 0.f, 0.f, 0.f};
#pragma unroll
    for (int n = 0; n < KVB / 16; ++n)
#pragma unroll
      for (int j = 0; j < 4; ++j) {
        float p = __expf(s[n][j] - mrow[j]);
        s[n][j] = p;
        rs[j] += p;
      }
#pragma unroll
    for (int j = 0; j < 4; ++j) {
      rs[j] += __shfl_xor(rs[j], 1, 64);
      rs[j] += __shfl_xor(rs[j], 2, 64);
      rs[j] += __shfl_xor(rs[j], 4, 64);
      rs[j] += __shfl_xor(rs[j], 8, 64);
      lrow[j] = lrow[j] * corr[j] + rs[j];
    }
#pragma unroll
    for (int n = 0; n < 4; ++n)
#pragma unroll
      for (int j = 0; j < 4; ++j) acc[n][j] *= corr[j];

    // P (D-layout) -> LDS -> A-layout fragments (same-wave DS ops are ordered)
#pragma unroll
    for (int n = 0; n < KVB / 16; ++n)
#pragma unroll
      for (int j = 0; j < 4; ++j)
        Pl[wave][4 * lg + j][n * 16 + l15] = f2bf(s[n][j]);
    // PV: out[q][dk] += P[q][kv] * V[kv][dk]
#pragma unroll
    for (int kc2 = 0; kc2 < KVB / 32; ++kc2) {
      bf16x8 pf = *(const bf16x8*)&Pl[wave][l15][kc2 * 32 + 8 * lg];
#pragma unroll
      for (int nd = 0; nd < 4; ++nd) {
        bf16x8 vf = *(const bf16x8*)&Vt[nd * 16 + l15][kc2 * 32 + 8 * lg];
        acc[nd] = __builtin_amdgcn_mfma_f32_16x16x32_bf16(pf, vf, acc[nd], 0, 0, 0);
      }
    }
    __syncthreads();
  }
  // write O (bf16), row = qrow0 + wave*16 + 4*lg + j, col = h*64 + nd*16 + l15
#pragma unroll
  for (int nd = 0; nd < 4; ++nd) {
    int col = h * DKH + nd * 16 + l15;
#pragma unroll
    for (int j = 0; j < 4; ++j) {
      int row = qrow0 + wave * 16 + 4 * lg + j;
      float v = acc[nd][j] / lrow[j];
      Op[(size_t)row * D_MODEL + col] = f2bf(v);
    }
  }
}

// ---------------------------------------------------------------------------
extern "C" void kernel_launch(void* const* d_in, const int* in_sizes, int n_in,
                              void* d_out, int out_size, void* d_ws,
                              size_t ws_size, hipStream_t stream) {
  (void)in_sizes; (void)n_in; (void)out_size; (void)ws_size;
  const float* q   = (const float*)d_in[0];
  const float* k   = (const float*)d_in[1];
  const float* v   = (const float*)d_in[2];
  const float* w_q = (const float*)d_in[3];
  const float* b_q = (const float*)d_in[4];
  const float* w_k = (const float*)d_in[5];
  const float* b_k = (const float*)d_in[6];
  const float* w_v = (const float*)d_in[7];
  const float* b_v = (const float*)d_in[8];
  const float* w_o = (const float*)d_in[9];
  const float* b_o = (const float*)d_in[10];
  float* out = (float*)d_out;

  const size_t ACT = (size_t)MTOT * D_MODEL;     // 4M elems
  const size_t WEL = (size_t)D_MODEL * D_MODEL;  // 1M elems
  u16* qb  = (u16*)d_ws;        // bf16 workspace layout, 64 MB total
  u16* kb  = qb + ACT;
  u16* vb  = kb + ACT;
  u16* wqb = vb + ACT;
  u16* wkb = wqb + WEL;
  u16* wvb = wkb + WEL;
  u16* wob = wvb + WEL;
  u16* Qp  = wob + WEL;
  u16* Kp  = Qp + ACT;
  u16* Vp  = Kp + ACT;
  u16* Op  = Vp + ACT;

  const int na = (int)(ACT / 4), nw = (int)(WEL / 4);
  cvt_f32_bf16<<<na / 256, 256, 0, stream>>>(q, qb, na);
  cvt_f32_bf16<<<na / 256, 256, 0, stream>>>(k, kb, na);
  cvt_f32_bf16<<<na / 256, 256, 0, stream>>>(v, vb, na);
  cvt_f32_bf16<<<nw / 256, 256, 0, stream>>>(w_q, wqb, nw);
  cvt_f32_bf16<<<nw / 256, 256, 0, stream>>>(w_k, wkb, nw);
  cvt_f32_bf16<<<nw / 256, 256, 0, stream>>>(w_v, wvb, nw);
  cvt_f32_bf16<<<nw / 256, 256, 0, stream>>>(w_o, wob, nw);

  proj_kernel<<<dim3((MTOT / 128) * (D_MODEL / 128), 3, 1), 256, 0, stream>>>(
      qb, kb, vb, wqb, wkb, wvb, b_q, b_k, b_v, Qp, Kp, Vp);

  attn_kernel<<<dim3(SEQ / 64, NH, BATCH), 256, 0, stream>>>(Qp, Kp, Vp, Op);

  oproj_kernel<<<dim3((MTOT / 128) * (D_MODEL / 128)), 256, 0, stream>>>(
      Op, wob, b_o, out);
}

// Round 2
// 324.503 us; speedup vs baseline: 1.0185x; 1.0185x over previous
//
#include <hip/hip_runtime.h>
#include <cstdint>

// ---------------------------------------------------------------------------
// MultiHeadAttention fwd: B=2, S=2048, D=1024, H=16, d_k=64, fp32 in/out.
//   1) convert q,k,v + weights fp32 -> bf16 (2 launches)
//   2) fused 3-way projection GEMM_bt, Q scaled by 0.125*log2(e)
//   3) flash attention: 512 thr / 128 q-rows / KVB=128, XOR-swizzled LDS
//   4) output projection GEMM_bt -> fp32 d_out
// ---------------------------------------------------------------------------

typedef float  f32x4  __attribute__((ext_vector_type(4)));
typedef __bf16 bf16x8 __attribute__((ext_vector_type(8)));
typedef unsigned short u16;
typedef u16 u16x8 __attribute__((ext_vector_type(8)));

#define D_MODEL 1024
#define SEQ     2048
#define BATCH   2
#define NH      16
#define DKH     64
#define MTOT    (BATCH * SEQ)   // 4096
#define KVB     128
#define QB      128

#if __has_builtin(__builtin_amdgcn_exp2f)
#define EXP2(x) __builtin_amdgcn_exp2f(x)
#else
#define EXP2(x) exp2f(x)
#endif

__device__ __forceinline__ u16 f2bf(float f) {
  uint32_t u = __builtin_bit_cast(uint32_t, f);
  u = u + 0x7fffu + ((u >> 16) & 1u);   // RNE
  return (u16)(u >> 16);
}
__device__ __forceinline__ u16 f2bf_hw(float f) {   // via v_cvt (RNE)
  return __builtin_bit_cast(u16, (__bf16)f);
}

// async global->LDS, 16B per lane; dest = wave-uniform base + lane*16
__device__ __forceinline__ void gl_lds16(const void* g, void* l) {
  __builtin_amdgcn_global_load_lds(
      (__attribute__((address_space(1))) void*)(g),
      (__attribute__((address_space(3))) void*)(l), 16, 0, 0);
}

// ---------------------------------------------------------------------------
__device__ __forceinline__ void cvt_body(const float* __restrict__ in,
                                         u16* __restrict__ out, int i) {
  float4 v = reinterpret_cast<const float4*>(in)[i];
  uint32_t p0 = (uint32_t)f2bf(v.x) | ((uint32_t)f2bf(v.y) << 16);
  uint32_t p1 = (uint32_t)f2bf(v.z) | ((uint32_t)f2bf(v.w) << 16);
  reinterpret_cast<uint2*>(out)[i] = make_uint2(p0, p1);
}

__global__ __launch_bounds__(256) void cvt_qkv(
    const float* q, const float* k, const float* v,
    u16* qb, u16* kb, u16* vb) {
  int z = blockIdx.y;
  const float* in = (z == 0) ? q : (z == 1) ? k : v;
  u16* out = (z == 0) ? qb : (z == 1) ? kb : vb;
  cvt_body(in, out, blockIdx.x * 256 + threadIdx.x);
}

__global__ __launch_bounds__(256) void cvt_w(
    const float* w0, const float* w1, const float* w2, const float* w3,
    u16* o0, u16* o1, u16* o2, u16* o3) {
  int z = blockIdx.y;
  const float* in = (z == 0) ? w0 : (z == 1) ? w1 : (z == 2) ? w2 : w3;
  u16* out = (z == 0) ? o0 : (z == 1) ? o1 : (z == 2) ? o2 : o3;
  cvt_body(in, out, blockIdx.x * 256 + threadIdx.x);
}

// ---------------------------------------------------------------------------
// C[M][N] = A[M][K]*W[N][K]^T + bias, scaled. 128x128 tile, 256 thr, m97-style.
template <bool BF16OUT>
__device__ __forceinline__ void gemm_bt_body(
    const u16* __restrict__ A, const u16* __restrict__ W,
    const float* __restrict__ bias, void* __restrict__ Cout,
    int N, int K, float scale, int bidx) {
  __shared__ u16 As[128][64];
  __shared__ u16 Bs[128][64];
  const int nbx = N / 128;
  const int bx = bidx % nbx, by = bidx / nbx;
  const int tid = threadIdx.x, wave = tid >> 6, lane = tid & 63;
  const int l15 = lane & 15, lg = lane >> 4;
  const int wr = wave >> 1, wc = wave & 1;
  f32x4 acc[4][4] = {};
  const int rA = by * 128 + (lane >> 3);
  const int rB = bx * 128 + (lane >> 3);
  const int ccol = (lane & 7) * 8;

  for (int kt = 0; kt < K; kt += 64) {
    for (int c = wave; c < 16; c += 4) {
      gl_lds16(A + (size_t)(rA + 8 * c) * K + kt + ccol, &As[8 * c][0]);
      gl_lds16(W + (size_t)(rB + 8 * c) * K + kt + ccol, &Bs[8 * c][0]);
    }
    __syncthreads();
#pragma unroll
    for (int kc = 0; kc < 2; ++kc) {
      bf16x8 af[4], bw[4];
#pragma unroll
      for (int m = 0; m < 4; ++m)
        af[m] = *(const bf16x8*)&As[wr * 64 + m * 16 + l15][kc * 32 + 8 * lg];
#pragma unroll
      for (int n = 0; n < 4; ++n)
        bw[n] = *(const bf16x8*)&Bs[wc * 64 + n * 16 + l15][kc * 32 + 8 * lg];
#pragma unroll
      for (int m = 0; m < 4; ++m)
#pragma unroll
        for (int n = 0; n < 4; ++n)
          acc[m][n] = __builtin_amdgcn_mfma_f32_16x16x32_bf16(
              af[m], bw[n], acc[m][n], 0, 0, 0);
    }
    __syncthreads();
  }
#pragma unroll
  for (int n = 0; n < 4; ++n) {
    int col = bx * 128 + wc * 64 + n * 16 + l15;
    float bv = bias[col];
#pragma unroll
    for (int m = 0; m < 4; ++m) {
      int row0 = by * 128 + wr * 64 + m * 16 + 4 * lg;
#pragma unroll
      for (int j = 0; j < 4; ++j) {
        float v = (acc[m][n][j] + bv) * scale;
        if (BF16OUT)
          ((u16*)Cout)[(size_t)(row0 + j) * N + col] = f2bf(v);
        else
          ((float*)Cout)[(size_t)(row0 + j) * N + col] = v;
      }
    }
  }
}

#define SCALE_Q 0.18033688011112042f   // 0.125 * log2(e): softmax in base 2

__global__ __launch_bounds__(256) void proj_kernel(
    const u16* qb, const u16* kb, const u16* vb,
    const u16* wq, const u16* wk, const u16* wv,
    const float* b_q, const float* b_k, const float* b_v,
    u16* Qp, u16* Kp, u16* Vp) {
  int z = blockIdx.y;
  const u16* A = (z == 0) ? qb : (z == 1) ? kb : vb;
  const u16* W = (z == 0) ? wq : (z == 1) ? wk : wv;
  const float* bi = (z == 0) ? b_q : (z == 1) ? b_k : b_v;
  u16* O = (z == 0) ? Qp : (z == 1) ? Kp : Vp;
  float scale = (z == 0) ? SCALE_Q : 1.0f;
  gemm_bt_body<true>(A, W, bi, O, D_MODEL, D_MODEL, scale, blockIdx.x);
}

__global__ __launch_bounds__(256) void oproj_kernel(
    const u16* Op, const u16* wo, const float* b_o, float* out) {
  gemm_bt_body<false>(Op, wo, b_o, out, D_MODEL, D_MODEL, 1.0f, blockIdx.x);
}

// ---------------------------------------------------------------------------
// Flash attention. grid (S/128, H, B), 512 thr (8 waves; wave w owns q-rows
// [w*16, w*16+16)). All LDS XOR-swizzled: cell (row,col) stored at
// col ^ ((row&7)<<3)  [u16 units]; Vt additionally ^ ((row>>4)<<4).
// K/Q staged via global_load_lds with pre-swizzled GLOBAL source col
// (linear LDS dest), per rule #21.
__global__ __launch_bounds__(512, 4) void attn_kernel(
    const u16* __restrict__ Qp, const u16* __restrict__ Kp,
    const u16* __restrict__ Vp, u16* __restrict__ Op) {
  __shared__ u16 PlQ[8][16][128];   // 32KB; first 16KB doubles as Qs[128][64]
  __shared__ u16 Ks[KVB][64];       // 16KB
  __shared__ u16 Vt[64][KVB];       // 16KB  (V^T: row=dk, col=kv)
  const int qt = blockIdx.x, h = blockIdx.y, b = blockIdx.z;
  const int tid = threadIdx.x, wave = tid >> 6, lane = tid & 63;
  const int l15 = lane & 15, lg = lane >> 4;
  const int qrow0 = b * SEQ + qt * QB;
  u16* Qs = &PlQ[0][0][0];          // flat [128*64]

  const int srow = lane >> 3;                 // 0..7 (= staged row & 7)
  const int scol = 8 * ((lane & 7) ^ srow);   // pre-swizzled source col
  const int rxor = (l15 & 7) << 3;            // read-side swizzle

  // ---- stage Q (128 rows x 64), swizzled ----
  for (int c = wave; c < 16; c += 8)
    gl_lds16(Qp + (size_t)(qrow0 + 8 * c + srow) * D_MODEL + h * DKH + scol,
             Qs + (8 * c) * 64);
  __syncthreads();
  bf16x8 qf[2];
#pragma unroll
  for (int kc = 0; kc < 2; ++kc)
    qf[kc] =
        *(const bf16x8*)&Qs[(wave * 16 + l15) * 64 + ((kc * 32 + 8 * lg) ^ rxor)];
  // all qf reads complete at the first in-loop barrier; PlQ writes come after

  float mrow[4], lrow[4];
  f32x4 acc[4] = {};
#pragma unroll
  for (int j = 0; j < 4; ++j) { mrow[j] = -1e30f; lrow[j] = 0.f; }

  const int kvp = tid >> 3;     // 0..63: kv row-pair
  const int g   = tid & 7;      // 0..7:  dk 8-col group
  const int vgx = (g >> 1) << 4;

  for (int kt = 0; kt < SEQ / KVB; ++kt) {
    const int kv0 = b * SEQ + kt * KVB;
    // K stage (swizzled source, linear dest)
    for (int c = wave; c < 16; c += 8)
      gl_lds16(Kp + (size_t)(kv0 + 8 * c + srow) * D_MODEL + h * DKH + scol,
               &Ks[8 * c][0]);
    // V transpose-stage: thread covers kv rows {2kvp,2kvp+1}, dk cols 8g..8g+7
    {
      const u16* vs = Vp + (size_t)(kv0 + 2 * kvp) * D_MODEL + h * DKH + 8 * g;
      u16x8 r0 = *(const u16x8*)vs;
      u16x8 r1 = *(const u16x8*)(vs + D_MODEL);
#pragma unroll
      for (int d = 0; d < 8; ++d) {
        uint32_t wv = (uint32_t)r0[d] | ((uint32_t)r1[d] << 16);
        *(uint32_t*)&Vt[8 * g + d][(2 * kvp) ^ (d << 3) ^ vgx] = wv;
      }
    }
    __syncthreads();

    // QK^T: D[q=4lg+j][kv=n*16+l15]
    f32x4 s[KVB / 16] = {};
#pragma unroll
    for (int n = 0; n < KVB / 16; ++n)
#pragma unroll
      for (int kc = 0; kc < 2; ++kc) {
        bf16x8 kf =
            *(const bf16x8*)&Ks[n * 16 + l15][(kc * 32 + 8 * lg) ^ rxor];
        s[n] = __builtin_amdgcn_mfma_f32_16x16x32_bf16(qf[kc], kf, s[n], 0, 0, 0);
      }
    // online softmax in base 2 (log2e folded into Q projection)
    float corr[4];
#pragma unroll
    for (int j = 0; j < 4; ++j) {
      float v = s[0][j];
#pragma unroll
      for (int n = 1; n < KVB / 16; ++n) v = fmaxf(v, s[n][j]);
      v = fmaxf(v, __shfl_xor(v, 1, 64));
      v = fmaxf(v, __shfl_xor(v, 2, 64));
      v = fmaxf(v, __shfl_xor(v, 4, 64));
      v = fmaxf(v, __shfl_xor(v, 8, 64));
      float mnew = fmaxf(mrow[j], v);
      corr[j] = EXP2(mrow[j] - mnew);
      mrow[j] = mnew;
    }
    float rs[4] = {0.f, 0.f, 0.f, 0.f};
#pragma unroll
    for (int n = 0; n < KVB / 16; ++n)
#pragma unroll
      for (int j = 0; j < 4; ++j) {
        float p = EXP2(s[n][j] - mrow[j]);
        s[n][j] = p;
        rs[j] += p;
      }
#pragma unroll
    for (int j = 0; j < 4; ++j) {
      rs[j] += __shfl_xor(rs[j], 1, 64);
      rs[j] += __shfl_xor(rs[j], 2, 64);
      rs[j] += __shfl_xor(rs[j], 4, 64);
      rs[j] += __shfl_xor(rs[j], 8, 64);
      lrow[j] = lrow[j] * corr[j] + rs[j];
    }
#pragma unroll
    for (int n = 0; n < 4; ++n)
#pragma unroll
      for (int j = 0; j < 4; ++j) acc[n][j] *= corr[j];

    // P relayout via per-wave swizzled LDS slice
#pragma unroll
    for (int n = 0; n < KVB / 16; ++n)
#pragma unroll
      for (int j = 0; j < 4; ++j) {
        int row = 4 * lg + j;
        PlQ[wave][row][(n * 16 + l15) ^ ((row & 7) << 3)] = f2bf_hw(s[n][j]);
      }
    // PV: acc[nd] += P[q][kv] * V[kv][dk]
#pragma unroll
    for (int kc2 = 0; kc2 < KVB / 32; ++kc2) {
      bf16x8 pf =
          *(const bf16x8*)&PlQ[wave][l15][(kc2 * 32 + 8 * lg) ^ rxor];
#pragma unroll
      for (int nd = 0; nd < 4; ++nd) {
        bf16x8 vf = *(const bf16x8*)&Vt[nd * 16 + l15]
                                      [(kc2 * 32 + 8 * lg) ^ rxor ^ (nd << 4)];
        acc[nd] =
            __builtin_amdgcn_mfma_f32_16x16x32_bf16(pf, vf, acc[nd], 0, 0, 0);
      }
    }
    __syncthreads();
  }
  // O write: row = qrow0 + wave*16 + 4lg + j, col = h*64 + nd*16 + l15
  float rinv[4];
#pragma unroll
  for (int j = 0; j < 4; ++j) rinv[j] = 1.0f / lrow[j];
#pragma unroll
  for (int nd = 0; nd < 4; ++nd) {
    int col = h * DKH + nd * 16 + l15;
#pragma unroll
    for (int j = 0; j < 4; ++j) {
      int row = qrow0 + wave * 16 + 4 * lg + j;
      Op[(size_t)row * D_MODEL + col] = f2bf_hw(acc[nd][j] * rinv[j]);
    }
  }
}

// ---------------------------------------------------------------------------
extern "C" void kernel_launch(void* const* d_in, const int* in_sizes, int n_in,
                              void* d_out, int out_size, void* d_ws,
                              size_t ws_size, hipStream_t stream) {
  (void)in_sizes; (void)n_in; (void)out_size; (void)ws_size;
  const float* q   = (const float*)d_in[0];
  const float* k   = (const float*)d_in[1];
  const float* v   = (const float*)d_in[2];
  const float* w_q = (const float*)d_in[3];
  const float* b_q = (const float*)d_in[4];
  const float* w_k = (const float*)d_in[5];
  const float* b_k = (const float*)d_in[6];
  const float* w_v = (const float*)d_in[7];
  const float* b_v = (const float*)d_in[8];
  const float* w_o = (const float*)d_in[9];
  const float* b_o = (const float*)d_in[10];
  float* out = (float*)d_out;

  const size_t ACT = (size_t)MTOT * D_MODEL;     // 4M elems
  const size_t WEL = (size_t)D_MODEL * D_MODEL;  // 1M elems
  u16* qb  = (u16*)d_ws;
  u16* kb  = qb + ACT;
  u16* vb  = kb + ACT;
  u16* wqb = vb + ACT;
  u16* wkb = wqb + WEL;
  u16* wvb = wkb + WEL;
  u16* wob = wvb + WEL;
  u16* Qp  = wob + WEL;
  u16* Kp  = Qp + ACT;
  u16* Vp  = Kp + ACT;
  u16* Op  = Vp + ACT;

  const int na = (int)(ACT / 4), nw = (int)(WEL / 4);
  cvt_qkv<<<dim3(na / 256, 3), 256, 0, stream>>>(q, k, v, qb, kb, vb);
  cvt_w<<<dim3(nw / 256, 4), 256, 0, stream>>>(w_q, w_k, w_v, w_o,
                                               wqb, wkb, wvb, wob);

  proj_kernel<<<dim3((MTOT / 128) * (D_MODEL / 128), 3), 256, 0, stream>>>(
      qb, kb, vb, wqb, wkb, wvb, b_q, b_k, b_v, Qp, Kp, Vp);

  attn_kernel<<<dim3(SEQ / QB, NH, BATCH), 512, 0, stream>>>(Qp, Kp, Vp, Op);

  oproj_kernel<<<dim3((MTOT / 128) * (D_MODEL / 128)), 256, 0, stream>>>(
      Op, wob, b_o, out);
}

// Round 6
// 248.984 us; speedup vs baseline: 1.3274x; 1.3033x over previous
//
#include <hip/hip_runtime.h>
#include <cstdint>

// ---------------------------------------------------------------------------
// MultiHeadAttention fwd: B=2, S=2048, D=1024, H=16, d_k=64, fp32 in/out.
//   1) convert q,k,v + weights fp32 -> bf16
//   2) fused 3-way projection GEMM_bt -> head-major [B,H,S,64] bf16,
//      Q scaled by 0.125*log2(e)
//   3) flash attention: 8 waves x 32 q-rows, KVB=64, swapped QK^T
//      (lane owns a q-row), per-lane softmax, P via per-wave swizzled LDS
//      (overlaid on Q buffer), swapped PV, K/V double-buffer prefetch.
//   4) output projection GEMM_bt (head-major A) -> fp32 d_out
// ---------------------------------------------------------------------------

typedef float  f32x4   __attribute__((ext_vector_type(4)));
typedef float  f32x16  __attribute__((ext_vector_type(16)));
typedef __bf16 bf16x8  __attribute__((ext_vector_type(8)));
typedef unsigned short u16;
typedef u16 u16x4 __attribute__((ext_vector_type(4)));
typedef u16 u16x8 __attribute__((ext_vector_type(8)));

#define D_MODEL 1024
#define SEQ     2048
#define BATCH   2
#define NH      16
#define DKH     64
#define MTOT    (BATCH * SEQ)   // 4096
#define KVB     64
#define QBLK    256
#define HSTRIDE ((size_t)SEQ * DKH)   // elems per (b,h) head-plane

#if __has_builtin(__builtin_amdgcn_exp2f)
#define EXP2(x) __builtin_amdgcn_exp2f(x)
#else
#define EXP2(x) exp2f(x)
#endif

__device__ __forceinline__ u16 f2bf(float f) {
  uint32_t u = __builtin_bit_cast(uint32_t, f);
  u = u + 0x7fffu + ((u >> 16) & 1u);   // RNE
  return (u16)(u >> 16);
}
__device__ __forceinline__ u16 f2bf_hw(float f) {
  return __builtin_bit_cast(u16, (__bf16)f);
}

// async global->LDS, 16B/lane; dest = wave-uniform base + lane*16
__device__ __forceinline__ void gl_lds16(const void* g, void* l) {
  __builtin_amdgcn_global_load_lds(
      (__attribute__((address_space(1))) void*)(g),
      (__attribute__((address_space(3))) void*)(l), 16, 0, 0);
}

// ---------------------------------------------------------------------------
__device__ __forceinline__ void cvt_body(const float* __restrict__ in,
                                         u16* __restrict__ out, int i) {
  float4 v = reinterpret_cast<const float4*>(in)[i];
  uint32_t p0 = (uint32_t)f2bf(v.x) | ((uint32_t)f2bf(v.y) << 16);
  uint32_t p1 = (uint32_t)f2bf(v.z) | ((uint32_t)f2bf(v.w) << 16);
  reinterpret_cast<uint2*>(out)[i] = make_uint2(p0, p1);
}

__global__ __launch_bounds__(256) void cvt_qkv(
    const float* q, const float* k, const float* v,
    u16* qb, u16* kb, u16* vb) {
  int z = blockIdx.y;
  const float* in = (z == 0) ? q : (z == 1) ? k : v;
  u16* out = (z == 0) ? qb : (z == 1) ? kb : vb;
  cvt_body(in, out, blockIdx.x * 256 + threadIdx.x);
}

__global__ __launch_bounds__(256) void cvt_w(
    const float* w0, const float* w1, const float* w2, const float* w3,
    u16* o0, u16* o1, u16* o2, u16* o3) {
  int z = blockIdx.y;
  const float* in = (z == 0) ? w0 : (z == 1) ? w1 : (z == 2) ? w2 : w3;
  u16* out = (z == 0) ? o0 : (z == 1) ? o1 : (z == 2) ? o2 : o3;
  cvt_body(in, out, blockIdx.x * 256 + threadIdx.x);
}

// ---------------------------------------------------------------------------
// C[M][N] = A[M][K]*W[N][K]^T + bias, scaled. 128x128 tile, 256 thr.
// HEADA: A is head-major [B,NH,SEQ,64]; HEADC: C written head-major bf16.
template <bool BF16OUT, bool HEADA, bool HEADC>
__device__ __forceinline__ void gemm_bt_body(
    const u16* __restrict__ A, const u16* __restrict__ W,
    const float* __restrict__ bias, void* __restrict__ Cout,
    int N, int K, float scale, int bidx) {
  __shared__ u16 As[128][64];
  __shared__ u16 Bs[128][64];
  const int nbx = N / 128;
  const int bx = bidx % nbx, by = bidx / nbx;
  const int tid = threadIdx.x, wave = tid >> 6, lane = tid & 63;
  const int l15 = lane & 15, lg = lane >> 4;
  const int wr = wave >> 1, wc = wave & 1;
  f32x4 acc[4][4] = {};
  const int rA = by * 128 + (lane >> 3);
  const int rB = bx * 128 + (lane >> 3);
  const int ccol = (lane & 7) * 8;

  for (int kt = 0; kt < K; kt += 64) {
    for (int c = wave; c < 16; c += 4) {
      if (HEADA) {
        int m = rA + 8 * c;
        size_t a_off = (size_t)((m >> 11) * NH + (kt >> 6)) * HSTRIDE +
                       (size_t)(m & (SEQ - 1)) * 64 + ccol;
        gl_lds16(A + a_off, &As[8 * c][0]);
      } else {
        gl_lds16(A + (size_t)(rA + 8 * c) * K + kt + ccol, &As[8 * c][0]);
      }
      gl_lds16(W + (size_t)(rB + 8 * c) * K + kt + ccol, &Bs[8 * c][0]);
    }
    __syncthreads();
#pragma unroll
    for (int kc = 0; kc < 2; ++kc) {
      bf16x8 af[4], bw[4];
#pragma unroll
      for (int m = 0; m < 4; ++m)
        af[m] = *(const bf16x8*)&As[wr * 64 + m * 16 + l15][kc * 32 + 8 * lg];
#pragma unroll
      for (int n = 0; n < 4; ++n)
        bw[n] = *(const bf16x8*)&Bs[wc * 64 + n * 16 + l15][kc * 32 + 8 * lg];
#pragma unroll
      for (int m = 0; m < 4; ++m)
#pragma unroll
        for (int n = 0; n < 4; ++n)
          acc[m][n] = __builtin_amdgcn_mfma_f32_16x16x32_bf16(
              af[m], bw[n], acc[m][n], 0, 0, 0);
    }
    __syncthreads();
  }
#pragma unroll
  for (int n = 0; n < 4; ++n) {
    int col = bx * 128 + wc * 64 + n * 16 + l15;
    float bv = bias[col];
#pragma unroll
    for (int m = 0; m < 4; ++m) {
      int row0 = by * 128 + wr * 64 + m * 16 + 4 * lg;
#pragma unroll
      for (int j = 0; j < 4; ++j) {
        float v = (acc[m][n][j] + bv) * scale;
        int row = row0 + j;
        if (HEADC) {
          size_t off = (size_t)((row >> 11) * NH + (col >> 6)) * HSTRIDE +
                       (size_t)(row & (SEQ - 1)) * 64 + (col & 63);
          ((u16*)Cout)[off] = f2bf(v);
        } else if (BF16OUT) {
          ((u16*)Cout)[(size_t)row * N + col] = f2bf(v);
        } else {
          ((float*)Cout)[(size_t)row * N + col] = v;
        }
      }
    }
  }
}

#define SCALE_Q 0.18033688011112042f   // 0.125 * log2(e)

__global__ __launch_bounds__(256) void proj_kernel(
    const u16* qb, const u16* kb, const u16* vb,
    const u16* wq, const u16* wk, const u16* wv,
    const float* b_q, const float* b_k, const float* b_v,
    u16* Qp, u16* Kp, u16* Vp) {
  int z = blockIdx.y;
  const u16* A = (z == 0) ? qb : (z == 1) ? kb : vb;
  const u16* W = (z == 0) ? wq : (z == 1) ? wk : wv;
  const float* bi = (z == 0) ? b_q : (z == 1) ? b_k : b_v;
  u16* O = (z == 0) ? Qp : (z == 1) ? Kp : Vp;
  float scale = (z == 0) ? SCALE_Q : 1.0f;
  gemm_bt_body<true, false, true>(A, W, bi, O, D_MODEL, D_MODEL, scale,
                                  blockIdx.x);
}

__global__ __launch_bounds__(256) void oproj_kernel(
    const u16* Op, const u16* wo, const float* b_o, float* out) {
  gemm_bt_body<false, true, false>(Op, wo, b_o, out, D_MODEL, D_MODEL, 1.0f,
                                   blockIdx.x);
}

// ---------------------------------------------------------------------------
// Flash attention, swapped-operand 32x32 structure.
// grid 256 blocks x 512 thr. bid = qt*32 + g, g = b*NH+h. Wave w owns q-rows
// [32w, 32w+32): its QPl slice (rows 32w..32w+31) serves as Q-stage, then
// per-wave P buffer, then O-stage — no cross-wave hazard on that slice.
// Lane owns q = 32*wave + (lane&31); hi = lane>>5.
// QK^T D-layout: s[t][r] = S[kv=32t+crow(r,hi)][q], crow=(r&3)+8*(r>>2)+4*hi.
__global__ __launch_bounds__(512, 2) void attn_kernel(
    const u16* __restrict__ Qh, const u16* __restrict__ Kh,
    const u16* __restrict__ Vh, u16* __restrict__ Oh) {
  __shared__ u16 QPl[QBLK * 64];    // 32KB: Q stage -> per-wave P -> O stage
  __shared__ u16 Ks[2][KVB * 64];   // 8KB x2, chunk ^= (row&7)
  __shared__ u16 Vt[2][64 * KVB];   // 8KB x2, V^T, chunk ^= ((dk>>2)&7)
  const int bid = blockIdx.x;
  const int g = bid & 31, qt = bid >> 5;
  const size_t base = (size_t)g * HSTRIDE;
  const int tid = threadIdx.x, wave = tid >> 6, lane = tid & 63;
  const int l31 = lane & 31, hi = lane >> 5;
  const int q0 = qt * QBLK;
  const int srow = lane >> 3;
  const int scol = 8 * ((lane & 7) ^ srow);   // pre-swizzled source col

  // ---- stage Q (256x64) ----
  for (int c = wave; c < 32; c += 8)
    gl_lds16(Qh + base + (size_t)(q0 + 8 * c + srow) * 64 + scol,
             QPl + 8 * c * 64);
  // ---- stage K tile 0, load V tile 0 to regs ----
  gl_lds16(Kh + base + (size_t)(8 * wave + srow) * 64 + scol,
           Ks[0] + 8 * wave * 64);
  const int vp = tid >> 4, vq = tid & 15;   // kv-pair 0..31, dk-quad 0..15
  u16x4 va, vb;
  {
    const u16* vsrc = Vh + base + (size_t)(2 * vp) * 64 + vq * 4;
    va = *(const u16x4*)vsrc;
    vb = *(const u16x4*)(vsrc + 64);
  }
  asm volatile("s_waitcnt vmcnt(0)" ::: "memory");
  __syncthreads();
#pragma unroll
  for (int j = 0; j < 4; ++j) {   // write V tile 0 (transposed, packed pairs)
    int dk = vq * 4 + j;
    uint32_t wv = (uint32_t)va[j] | ((uint32_t)vb[j] << 16);
    *(uint32_t*)&Vt[0][dk * 64 + (((vp >> 2) ^ (vq & 7)) << 3) + (vp & 3) * 2] =
        wv;
  }
  __syncthreads();

  // ---- Q fragments: qf[kk] = Q[q=32w+l31][16kk + 8hi + 0..7] ----
  bf16x8 qf[4];
#pragma unroll
  for (int kk = 0; kk < 4; ++kk) {
    int row = wave * 32 + l31;
    qf[kk] = *(const bf16x8*)&QPl[row * 64 + (((2 * kk + hi) ^ (row & 7)) << 3)];
  }
  // per-wave P buffer overlays this wave's own Q rows (now consumed)
  u16* Pw = QPl + wave * 32 * 64;   // [32 q][64 kv], chunk ^= (q&7)

  float mrow = -3e38f, lrow = 0.f;
  f32x16 acc[2] = {};

  for (int kt = 0; kt < SEQ / KVB; ++kt) {
    const int cur = kt & 1, nxt = cur ^ 1;
    if (kt + 1 < SEQ / KVB) {   // prefetch next tile: K->LDS(nxt), V->regs
      const size_t kv0 = base + (size_t)(kt + 1) * KVB * 64;
      gl_lds16(Kh + kv0 + (size_t)(8 * wave + srow) * 64 + scol,
               Ks[nxt] + 8 * wave * 64);
      const u16* vsrc = Vh + kv0 + (size_t)(2 * vp) * 64 + vq * 4;
      va = *(const u16x4*)vsrc;
      vb = *(const u16x4*)(vsrc + 64);
    }
    // ---- QK^T (swapped): s[t][r] = S[kv=32t+crow(r,hi)][q=l31] ----
    f32x16 s[2] = {};
#pragma unroll
    for (int t = 0; t < 2; ++t)
#pragma unroll
      for (int kk = 0; kk < 4; ++kk) {
        int row = t * 32 + l31;
        bf16x8 kf = *(const bf16x8*)&Ks[cur][row * 64 +
                                             (((2 * kk + hi) ^ (row & 7)) << 3)];
        s[t] = __builtin_amdgcn_mfma_f32_32x32x16_bf16(kf, qf[kk], s[t], 0, 0, 0);
      }
    // ---- online softmax (base-2), per-lane; halves merge via shfl_xor 32 ----
    float mx[16];
#pragma unroll
    for (int r = 0; r < 16; ++r) mx[r] = fmaxf(s[0][r], s[1][r]);
#pragma unroll
    for (int st2 = 8; st2 >= 1; st2 >>= 1)
#pragma unroll
      for (int r = 0; r < st2; ++r) mx[r] = fmaxf(mx[r], mx[r + st2]);
    float mtile = fmaxf(mx[0], __shfl_xor(mx[0], 32, 64));
    float mnew = fmaxf(mrow, mtile);
    float corr = EXP2(mrow - mnew);
    mrow = mnew;
    float sm0 = 0.f, sm1 = 0.f, sm2 = 0.f, sm3 = 0.f;
#pragma unroll
    for (int t = 0; t < 2; ++t)
#pragma unroll
      for (int r = 0; r < 16; r += 4) {
        float p0 = EXP2(s[t][r] - mnew);
        float p1 = EXP2(s[t][r + 1] - mnew);
        float p2 = EXP2(s[t][r + 2] - mnew);
        float p3 = EXP2(s[t][r + 3] - mnew);
        s[t][r] = p0; s[t][r + 1] = p1; s[t][r + 2] = p2; s[t][r + 3] = p3;
        sm0 += p0; sm1 += p1; sm2 += p2; sm3 += p3;
      }
    float psum = (sm0 + sm1) + (sm2 + sm3);
    lrow = lrow * corr + (psum + __shfl_xor(psum, 32, 64));
#pragma unroll
    for (int nd = 0; nd < 2; ++nd)
#pragma unroll
      for (int r = 0; r < 16; ++r) acc[nd][r] *= corr;

    // ---- P -> per-wave LDS (swizzled).  s[t][4b+m] = P[kv=32t+8b+4hi+m][q].
    // store run of 4 at row q, chunk (4t+b)^(q&7), offset 4hi ----
#pragma unroll
    for (int t = 0; t < 2; ++t)
#pragma unroll
      for (int b2 = 0; b2 < 4; ++b2) {
        u16x4 pk = {f2bf_hw(s[t][4 * b2]), f2bf_hw(s[t][4 * b2 + 1]),
                    f2bf_hw(s[t][4 * b2 + 2]), f2bf_hw(s[t][4 * b2 + 3])};
        *(u16x4*)&Pw[l31 * 64 + (((4 * t + b2) ^ (l31 & 7)) << 3) + 4 * hi] = pk;
      }
    // ---- PV (swapped): acc[nd] += V^T x P; B-frag kv=16ks+8hi+j at
    // chunk (2ks+hi)^(q&7) ----
#pragma unroll
    for (int ks = 0; ks < 4; ++ks) {
      bf16x8 pf =
          *(const bf16x8*)&Pw[l31 * 64 + (((2 * ks + hi) ^ (l31 & 7)) << 3)];
#pragma unroll
      for (int nd = 0; nd < 2; ++nd) {
        int dkr = nd * 32 + l31;
        bf16x8 vf = *(const bf16x8*)&Vt[cur][dkr * 64 +
                        (((2 * ks + hi) ^ ((l31 >> 2) & 7)) << 3)];
        acc[nd] =
            __builtin_amdgcn_mfma_f32_32x32x16_bf16(vf, pf, acc[nd], 0, 0, 0);
      }
    }
    asm volatile("s_waitcnt vmcnt(0)" ::: "memory");
    __syncthreads();                      // reads of cur done; K[nxt] landed
    if (kt + 1 < SEQ / KVB) {
#pragma unroll
      for (int j = 0; j < 4; ++j) {       // write V tile nxt
        int dk = vq * 4 + j;
        uint32_t wv = (uint32_t)va[j] | ((uint32_t)vb[j] << 16);
        *(uint32_t*)&Vt[nxt][dk * 64 + (((vp >> 2) ^ (vq & 7)) << 3) +
                             (vp & 3) * 2] = wv;
      }
    }
    __syncthreads();                      // nxt visible
  }

  // ---- epilogue: O^T regs -> LDS transpose (own wave slice) -> global ----
  float rinv = 1.0f / lrow;
  u16* Os = QPl;
  {
    int row = wave * 32 + l31;
#pragma unroll
    for (int nd = 0; nd < 2; ++nd)
#pragma unroll
      for (int b2 = 0; b2 < 4; ++b2) {
        // cols nd*32 + 8*b2 + 4*hi + (0..3)  <- acc[nd][4*b2 + 0..3]
        u16x4 ok = {f2bf_hw(acc[nd][4 * b2] * rinv),
                    f2bf_hw(acc[nd][4 * b2 + 1] * rinv),
                    f2bf_hw(acc[nd][4 * b2 + 2] * rinv),
                    f2bf_hw(acc[nd][4 * b2 + 3] * rinv)};
        *(u16x4*)&Os[row * 64 + (((4 * nd + b2) ^ (row & 7)) << 3) + 4 * hi] =
            ok;
      }
  }
  __syncthreads();
  {
    const int row = tid >> 1, half = tid & 1;
    u16* gp = (u16*)(Oh + base + (size_t)(q0 + row) * 64 + half * 32);
#pragma unroll
    for (int c2 = 0; c2 < 4; ++c2) {
      int pc = (half * 4 + c2) ^ (row & 7);
      *(u16x8*)(gp + c2 * 8) = *(const u16x8*)&Os[row * 64 + pc * 8];
    }
  }
}

// ---------------------------------------------------------------------------
extern "C" void kernel_launch(void* const* d_in, const int* in_sizes, int n_in,
                              void* d_out, int out_size, void* d_ws,
                              size_t ws_size, hipStream_t stream) {
  (void)in_sizes; (void)n_in; (void)out_size; (void)ws_size;
  const float* q   = (const float*)d_in[0];
  const float* k   = (const float*)d_in[1];
  const float* v   = (const float*)d_in[2];
  const float* w_q = (const float*)d_in[3];
  const float* b_q = (const float*)d_in[4];
  const float* w_k = (const float*)d_in[5];
  const float* b_k = (const float*)d_in[6];
  const float* w_v = (const float*)d_in[7];
  const float* b_v = (const float*)d_in[8];
  const float* w_o = (const float*)d_in[9];
  const float* b_o = (const float*)d_in[10];
  float* out = (float*)d_out;

  const size_t ACT = (size_t)MTOT * D_MODEL;     // 4M elems
  const size_t WEL = (size_t)D_MODEL * D_MODEL;  // 1M elems
  u16* qb  = (u16*)d_ws;
  u16* kb  = qb + ACT;
  u16* vb  = kb + ACT;
  u16* wqb = vb + ACT;
  u16* wkb = wqb + WEL;
  u16* wvb = wkb + WEL;
  u16* wob = wvb + WEL;
  u16* Qp  = wob + WEL;   // head-major [B,NH,SEQ,64]
  u16* Kp  = Qp + ACT;
  u16* Vp  = Kp + ACT;
  u16* Op  = Vp + ACT;

  const int na = (int)(ACT / 4), nw = (int)(WEL / 4);
  cvt_qkv<<<dim3(na / 256, 3), 256, 0, stream>>>(q, k, v, qb, kb, vb);
  cvt_w<<<dim3(nw / 256, 4), 256, 0, stream>>>(w_q, w_k, w_v, w_o,
                                               wqb, wkb, wvb, wob);

  proj_kernel<<<dim3((MTOT / 128) * (D_MODEL / 128), 3), 256, 0, stream>>>(
      qb, kb, vb, wqb, wkb, wvb, b_q, b_k, b_v, Qp, Kp, Vp);

  attn_kernel<<<dim3(BATCH * NH * (SEQ / QBLK)), 512, 0, stream>>>(Qp, Kp, Vp,
                                                                   Op);

  oproj_kernel<<<dim3((MTOT / 128) * (D_MODEL / 128)), 256, 0, stream>>>(
      Op, wob, b_o, out);
}